// Round 22
// baseline (141.286 us; speedup 1.0000x reference)
//
#include <hip/hip_runtime.h>
#include <math.h>

#define NS 4
#define HDIM 1024
#define DDIM 4096           // NS*HDIM
#define T 4                 // tokens per group
#define GRP 8               // groups per block (block owns 32 consecutive tokens)
#define NTH 512             // 8 waves
#define HC_EPS_F 1e-6f
#define NORM_EPS_F 1e-6f

__device__ __forceinline__ float frcp(float v) { return __builtin_amdgcn_rcpf(v); }

__device__ __forceinline__ void gload_lds16(const float* g, float* l) {
  __builtin_amdgcn_global_load_lds(
      (const __attribute__((address_space(1))) void*)g,
      (__attribute__((address_space(3))) void*)l, 16, 0, 0);
}

// LDS-only barrier: orders LDS data across waves WITHOUT draining vmcnt,
// so the in-flight gload_lds stage of the next group keeps flying (R20 lesson:
// full drains inside the loop serialize the pipeline).
#define SOFT_BARRIER()                                          \
  do {                                                          \
    asm volatile("s_waitcnt lgkmcnt(0)" ::: "memory");          \
    __builtin_amdgcn_sched_barrier(0);                          \
    __builtin_amdgcn_s_barrier();                               \
    __builtin_amdgcn_sched_barrier(0);                          \
  } while (0)

// ============ ONE-PASS, cross-group pipelined: stage(g+1) flies under B/C/D(g). ============
__launch_bounds__(NTH, 2)
__global__ void mhc_onepass(const float* __restrict__ x,
                            const float* __restrict__ hc_fn,
                            const float* __restrict__ hc_scale,
                            const float* __restrict__ hc_base,
                            float* __restrict__ out) {
  __shared__ float xs[2][T * DDIM];    // 128 KB double buffer -> 1 block/CU
  __shared__ float w_s[25][T];         // 24 dots + ssq
  __shared__ float g_s[24][T];         // gates

  const int tid  = threadIdx.x;
  const int lane = tid & 63;
  const int wave = tid >> 6;
  const long long btok0 = (long long)blockIdx.x * (T * GRP);  // 32 tokens/block

  const int mb = wave * 3;             // wave owns m-rows [3w, 3w+3)
  const float4* fn4[3];
  #pragma unroll
  for (int m = 0; m < 3; ++m)
    fn4[m] = (const float4*)(hc_fn + (long long)(mb + m) * DDIM);

  const float s0 = hc_scale[0], s1 = hc_scale[1], s2 = hc_scale[2];

  // ---- prologue: stage group 0 into buf 0 ----
  {
    const float* xg = x + btok0 * DDIM;
    #pragma unroll
    for (int c = 0; c < 8; ++c)
      gload_lds16(xg + (size_t)(c * NTH + tid) * 4,
                  xs[0] + (size_t)(c * NTH + wave * 64) * 4);
  }
  __syncthreads();                     // buf0 ready

  for (int g = 0; g < GRP; ++g) {
    const int cb = g & 1;
    const long long tok0 = btok0 + (long long)g * T;

    // ---- issue stage(g+1) into the other buffer; it flies under B/C/D ----
    if (g < GRP - 1) {
      const float* xg = x + (tok0 + T) * DDIM;
      #pragma unroll
      for (int c = 0; c < 8; ++c)
        gload_lds16(xg + (size_t)(c * NTH + tid) * 4,
                    xs[cb ^ 1] + (size_t)(c * NTH + wave * 64) * 4);
    }

    // ---- Phase B: 24 dots + ssq from LDS; fn 1-deep prefetch (L2-hot) ----
    float acc[3][T];
    #pragma unroll
    for (int m = 0; m < 3; ++m)
      #pragma unroll
      for (int t = 0; t < T; ++t) acc[m][t] = 0.f;
    float ssq = 0.f;                   // waves 0-3: ssq of token `wave`

    float4 c_fn[3];
    #pragma unroll
    for (int m = 0; m < 3; ++m) c_fn[m] = fn4[m][lane];

    const float4* xs4 = (const float4*)xs[cb];
    #pragma unroll 2
    for (int it = 0; it < 16; ++it) {
      float4 n_fn[3];
      if (it < 15) {
        const int nfl = (it + 1) * 64 + lane;
        #pragma unroll
        for (int m = 0; m < 3; ++m) n_fn[m] = fn4[m][nfl];
      }
      const int fl = it * 64 + lane;
      const float4 xv0 = xs4[fl];
      const float4 xv1 = xs4[1024 + fl];
      const float4 xv2 = xs4[2048 + fl];
      const float4 xv3 = xs4[3072 + fl];

      if (wave < 4) {
        const float4 xw = (wave == 0) ? xv0 : (wave == 1) ? xv1 : (wave == 2) ? xv2 : xv3;
        ssq = fmaf(xw.x, xw.x, fmaf(xw.y, xw.y, fmaf(xw.z, xw.z, fmaf(xw.w, xw.w, ssq))));
      }
      #pragma unroll
      for (int m = 0; m < 3; ++m) {
        acc[m][0] = fmaf(xv0.x, c_fn[m].x, fmaf(xv0.y, c_fn[m].y,
                    fmaf(xv0.z, c_fn[m].z, fmaf(xv0.w, c_fn[m].w, acc[m][0]))));
        acc[m][1] = fmaf(xv1.x, c_fn[m].x, fmaf(xv1.y, c_fn[m].y,
                    fmaf(xv1.z, c_fn[m].z, fmaf(xv1.w, c_fn[m].w, acc[m][1]))));
        acc[m][2] = fmaf(xv2.x, c_fn[m].x, fmaf(xv2.y, c_fn[m].y,
                    fmaf(xv2.z, c_fn[m].z, fmaf(xv2.w, c_fn[m].w, acc[m][2]))));
        acc[m][3] = fmaf(xv3.x, c_fn[m].x, fmaf(xv3.y, c_fn[m].y,
                    fmaf(xv3.z, c_fn[m].z, fmaf(xv3.w, c_fn[m].w, acc[m][3]))));
      }
      if (it < 15) {
        #pragma unroll
        for (int m = 0; m < 3; ++m) c_fn[m] = n_fn[m];
      }
    }

    // reduce: 12 values/wave (+ ssq on waves 0-3) -> w_s
    #pragma unroll
    for (int m = 0; m < 3; ++m)
      #pragma unroll
      for (int t = 0; t < T; ++t) {
        float v = acc[m][t];
        #pragma unroll
        for (int off = 32; off > 0; off >>= 1) v += __shfl_xor(v, off, 64);
        if (lane == 0) w_s[mb + m][t] = v;
      }
    if (wave < 4) {
      float v = ssq;
      #pragma unroll
      for (int off = 32; off > 0; off >>= 1) v += __shfl_xor(v, off, 64);
      if (lane == 0) w_s[24][wave] = v;
    }
    SOFT_BARRIER();                    // w_s visible; stage(g+1) stays in flight

    // ---- Phase C: sinkhorn + gates on wave 0 (lane = tt*16 + e) ----
    if (wave == 0) {
      const int tt = lane >> 4;
      const int e  = lane & 15;        // i*4 + j
      const float rs = rsqrtf(w_s[24][tt] * (1.0f / DDIM) + NORM_EPS_F);

      float h = w_s[8 + e][tt] * rs * s2 + hc_base[8 + e];
      float mx = fmaxf(h, __shfl_xor(h, 1, 4));
      mx = fmaxf(mx, __shfl_xor(mx, 2, 4));
      float ex = expf(h - mx);
      float sm = ex + __shfl_xor(ex, 1, 4);
      sm += __shfl_xor(sm, 2, 4);
      h = ex * frcp(sm) + HC_EPS_F;
      float cs = h + __shfl_xor(h, 4, 16);
      cs += __shfl_xor(cs, 8, 16);
      h *= frcp(cs + HC_EPS_F);
      #pragma unroll 1
      for (int itn = 0; itn < 19; ++itn) {
        float rsum = h + __shfl_xor(h, 1, 4);
        rsum += __shfl_xor(rsum, 2, 4);
        h *= frcp(rsum + HC_EPS_F);
        float csum = h + __shfl_xor(h, 4, 16);
        csum += __shfl_xor(csum, 8, 16);
        h *= frcp(csum + HC_EPS_F);
      }
      g_s[8 + e][tt] = h;
      if (e < NS) {
        const float wp = w_s[e][tt] * rs;
        g_s[e][tt] = frcp(1.0f + expf(-(wp * s0 + hc_base[e]))) + HC_EPS_F;
        const float wq = w_s[NS + e][tt] * rs;
        g_s[NS + e][tt] = 2.0f * frcp(1.0f + expf(-(wq * s1 + hc_base[NS + e])));
      }
    }
    SOFT_BARRIER();                    // g_s visible; stage(g+1) still in flight

    // ---- Phase D: out from LDS-x + LDS-gates. wave -> (token tt, h-half). ----
    {
      const int tt   = wave >> 1;
      const int half = wave & 1;
      float hp[NS], hq[NS], hr[NS][NS];
      #pragma unroll
      for (int i = 0; i < NS; ++i) {
        hp[i] = g_s[i][tt];
        hq[i] = g_s[NS + i][tt];
        #pragma unroll
        for (int j = 0; j < NS; ++j) hr[i][j] = g_s[8 + i * NS + j][tt];
      }
      float4* ob = (float4*)(out + (tok0 + tt) * DDIM);
      #pragma unroll
      for (int c = 0; c < 2; ++c) {
        const int h4 = half * 128 + c * 64 + lane;   // float4-in-HDIM [0,256)
        float4 xv[NS];
        #pragma unroll
        for (int i = 0; i < NS; ++i) xv[i] = xs4[tt * 1024 + i * 256 + h4];
        float4 y;
        y.x = hp[0]*xv[0].x + hp[1]*xv[1].x + hp[2]*xv[2].x + hp[3]*xv[3].x;
        y.y = hp[0]*xv[0].y + hp[1]*xv[1].y + hp[2]*xv[2].y + hp[3]*xv[3].y;
        y.z = hp[0]*xv[0].z + hp[1]*xv[1].z + hp[2]*xv[2].z + hp[3]*xv[3].z;
        y.w = hp[0]*xv[0].w + hp[1]*xv[1].w + hp[2]*xv[2].w + hp[3]*xv[3].w;
        #pragma unroll
        for (int n = 0; n < NS; ++n) {
          float4 o;
          o.x = hq[n]*y.x + hr[0][n]*xv[0].x + hr[1][n]*xv[1].x + hr[2][n]*xv[2].x + hr[3][n]*xv[3].x;
          o.y = hq[n]*y.y + hr[0][n]*xv[0].y + hr[1][n]*xv[1].y + hr[2][n]*xv[2].y + hr[3][n]*xv[3].y;
          o.z = hq[n]*y.z + hr[0][n]*xv[0].z + hr[1][n]*xv[1].z + hr[2][n]*xv[2].z + hr[3][n]*xv[3].z;
          o.w = hq[n]*y.w + hr[0][n]*xv[0].w + hr[1][n]*xv[1].w + hr[2][n]*xv[2].w + hr[3][n]*xv[3].w;
          ob[n * 256 + h4] = o;
        }
      }
    }

    // Full barrier: cur buffer free for stage(g+2) + stage(g+1) drained (vmcnt 0)
    __syncthreads();
  }
}

extern "C" void kernel_launch(void* const* d_in, const int* in_sizes, int n_in,
                              void* d_out, int out_size, void* d_ws, size_t ws_size,
                              hipStream_t stream) {
  const float* x        = (const float*)d_in[0];
  const float* hc_fn    = (const float*)d_in[1];
  const float* hc_scale = (const float*)d_in[2];
  const float* hc_base  = (const float*)d_in[3];
  float* out = (float*)d_out;

  const int ntok = in_sizes[0] / DDIM;       // B*S = 8192
  const int grid = ntok / (T * GRP);         // 256 blocks = 1 per CU
  mhc_onepass<<<grid, NTH, 0, stream>>>(x, hc_fn, hc_scale, hc_base, out);
}